// Round 9
// baseline (423.166 us; speedup 1.0000x reference)
//
#include <hip/hip_runtime.h>
#include <hip/hip_bf16.h>
#include <math.h>

typedef __bf16 bf16;
typedef __attribute__((ext_vector_type(8))) __bf16 bf16x8;
typedef __attribute__((ext_vector_type(4))) __bf16 bf16x4;
typedef __attribute__((ext_vector_type(4))) short short4v;
typedef __attribute__((ext_vector_type(4))) float f32x4;

#define MFMA16(a,b,c)  __builtin_amdgcn_mfma_f32_16x16x32_bf16((a),(b),(c),0,0,0)
#define MFMAK16(a,b,c) __builtin_amdgcn_mfma_f32_16x16x16bf16_1k((a),(b),(c),0,0,0)

__device__ __forceinline__ void gload16(const void* gp, void* lp) {
  __builtin_amdgcn_global_load_lds(
      (const __attribute__((address_space(1))) void*)gp,
      (__attribute__((address_space(3))) void*)lp, 16, 0, 0);
}

// ---------------- x cast: fp32 -> bf16, 8 elems/thread ----------------
__global__ __launch_bounds__(256) void cast_x(
    const float* __restrict__ x, bf16* __restrict__ xb)
{
  size_t i = ((size_t)blockIdx.x*256 + threadIdx.x) * 8;
  f32x4 a = *(const f32x4*)(x+i);
  f32x4 b = *(const f32x4*)(x+i+4);
  bf16x8 o;
  #pragma unroll
  for (int j=0;j<4;j++) { o[j] = (bf16)a[j]; o[4+j] = (bf16)b[j]; }
  *(bf16x8*)(xb+i) = o;
}

// ---------------- transpose+cast of all 4 weights in one launch ----------------
__global__ __launch_bounds__(1024) void tr_cast4(
    const float* __restrict__ w0, const float* __restrict__ w1,
    const float* __restrict__ w2, const float* __restrict__ w3,
    bf16* __restrict__ dqkv, bf16* __restrict__ dO)
{
  __shared__ bf16 tile[64][65];
  const int z = blockIdx.z;
  const float* src = (z==0)?w0:(z==1)?w1:(z==2)?w2:w3;
  bf16* d = (z<3) ? (dqkv + (size_t)z*(1024*1024)) : dO;
  int x = threadIdx.x, y = threadIdx.y;
  int tc = blockIdx.x, tr = blockIdx.y;
  #pragma unroll
  for (int i=0;i<4;i++) {
    int r = y + i*16;
    tile[r][x] = (bf16)src[(size_t)(tr*64+r)*1024 + tc*64 + x];
  }
  __syncthreads();
  #pragma unroll
  for (int i=0;i<4;i++) {
    int r = y + i*16;
    d[(size_t)(tc*64+r)*1024 + tr*64 + x] = tile[x][r];
  }
}

// ---------------- fused QKV GEMM (unchanged control, m97 staging) ----------------
__global__ __launch_bounds__(256) void gemm_qkv(
    const bf16* __restrict__ A, const bf16* __restrict__ Bt,
    const float* __restrict__ bq, const float* __restrict__ bk, const float* __restrict__ bv,
    bf16* __restrict__ q, bf16* __restrict__ k, bf16* __restrict__ v,
    int M, int K)
{
  __shared__ __align__(16) bf16 As[128*32];
  __shared__ __align__(16) bf16 Bs[128*32];
  const int tid  = threadIdx.x;
  const int wave = tid >> 6;
  const int lane = tid & 63;
  const int l15  = lane & 15;
  const int quad = lane >> 4;
  const int m0 = blockIdx.y * 128;
  const int n0 = blockIdx.x * 128;
  const int wm = (wave >> 1) * 64;
  const int wn = (wave & 1) * 64;
  const int srow = lane >> 2;
  const int scol = (lane & 3) * 8;

  f32x4 acc[4][4];
  #pragma unroll
  for (int i=0;i<4;i++)
    #pragma unroll
    for (int j=0;j<4;j++)
      acc[i][j] = (f32x4){0.f,0.f,0.f,0.f};

  for (int k0 = 0; k0 < K; k0 += 32) {
    __syncthreads();
    #pragma unroll
    for (int p=0;p<2;p++) {
      int c = p*4 + wave;
      int row = c*16 + srow;
      gload16(A  + (size_t)(m0+row)*K + k0 + scol, As + c*512);
      gload16(Bt + (size_t)(n0+row)*K + k0 + scol, Bs + c*512);
    }
    __syncthreads();
    bf16x8 af[4], bfr[4];
    #pragma unroll
    for (int t=0;t<4;t++) {
      af[t]  = *(const bf16x8*)(As + (wm + t*16 + l15)*32 + quad*8);
      bfr[t] = *(const bf16x8*)(Bs + (wn + t*16 + l15)*32 + quad*8);
    }
    #pragma unroll
    for (int mt=0;mt<4;mt++)
      #pragma unroll
      for (int nt=0;nt<4;nt++)
        acc[mt][nt] = MFMA16(af[mt], bfr[nt], acc[mt][nt]);
  }

  const int mat = n0 >> 10;
  const float* bsel = (mat==0) ? bq : (mat==1) ? bk : bv;
  bf16*       osel  = (mat==0) ? q  : (mat==1) ? k  : v;
  #pragma unroll
  for (int nt=0;nt<4;nt++) {
    int col = n0 + wn + nt*16 + l15;
    int cw  = col & 1023;
    float bvv = bsel[cw];
    #pragma unroll
    for (int mt=0;mt<4;mt++) {
      int row = m0 + wm + mt*16 + quad*4;
      #pragma unroll
      for (int r=0;r<4;r++)
        osel[(size_t)(row + r)*1024 + cw] = (bf16)(acc[mt][nt][r] + bvv);
    }
  }
}

// ---------------- final GEMM (unchanged control) ----------------
__global__ __launch_bounds__(256) void gemm_out(
    const bf16* __restrict__ A, const bf16* __restrict__ Bt,
    const float* __restrict__ bias, float* __restrict__ C,
    int M, int N, int K)
{
  __shared__ __align__(16) bf16 As[128*32];
  __shared__ __align__(16) bf16 Bs[128*32];
  const int tid  = threadIdx.x;
  const int wave = tid >> 6;
  const int lane = tid & 63;
  const int l15  = lane & 15;
  const int quad = lane >> 4;
  const int m0 = blockIdx.y * 128;
  const int n0 = blockIdx.x * 128;
  const int wm = (wave >> 1) * 64;
  const int wn = (wave & 1) * 64;
  const int srow = lane >> 2;
  const int scol = (lane & 3) * 8;

  f32x4 acc[4][4];
  #pragma unroll
  for (int i=0;i<4;i++)
    #pragma unroll
    for (int j=0;j<4;j++)
      acc[i][j] = (f32x4){0.f,0.f,0.f,0.f};

  for (int k0 = 0; k0 < K; k0 += 32) {
    __syncthreads();
    #pragma unroll
    for (int p=0;p<2;p++) {
      int c = p*4 + wave;
      int row = c*16 + srow;
      gload16(A  + (size_t)(m0+row)*K + k0 + scol, As + c*512);
      gload16(Bt + (size_t)(n0+row)*K + k0 + scol, Bs + c*512);
    }
    __syncthreads();
    bf16x8 af[4], bfr[4];
    #pragma unroll
    for (int t=0;t<4;t++) {
      af[t]  = *(const bf16x8*)(As + (wm + t*16 + l15)*32 + quad*8);
      bfr[t] = *(const bf16x8*)(Bs + (wn + t*16 + l15)*32 + quad*8);
    }
    #pragma unroll
    for (int mt=0;mt<4;mt++)
      #pragma unroll
      for (int nt=0;nt<4;nt++)
        acc[mt][nt] = MFMA16(af[mt], bfr[nt], acc[mt][nt]);
  }

  #pragma unroll
  for (int nt=0;nt<4;nt++) {
    int col = n0 + wn + nt*16 + l15;
    float bvv = bias[col];
    #pragma unroll
    for (int mt=0;mt<4;mt++) {
      int row = m0 + wm + mt*16 + quad*4;
      #pragma unroll
      for (int r=0;r<4;r++)
        C[(size_t)(row + r)*N + col] = acc[mt][nt][r] + bvv;
    }
  }
}

// ---------------- flash attention, S^T formulation, 32 q-rows/wave ----------------
// Block = 128 q-rows (4 waves x 2 groups of 16q). Ks/Vt unchanged (36 KB, 4 blocks/CU).
// Grid 1024 = single fully-resident pass; qt mapping makes each CU's 4 resident
// blocks sum to a constant tile count (makespan-balanced).
__global__ __launch_bounds__(256, 4) void attn_fwd(
    const bf16* __restrict__ Q, const bf16* __restrict__ Kp,
    const bf16* __restrict__ V, bf16* __restrict__ O)
{
  __shared__ __align__(16) bf16 Ks[2*64*72];  // [buf][t][d] stride 72
  __shared__ __align__(16) bf16 Vt[2*64*72];  // [buf][d][t] stride 72

  const int tid  = threadIdx.x;
  const int w    = tid >> 6;
  const int lane = tid & 63;
  const int l15  = lane & 15;
  const int quad = lane >> 4;

  const int bid = blockIdx.x;
  const int bh  = bid & 31;                  // same-bh blocks land on one XCD (32 % 8 == 0)
  const int j   = bid >> 5;                  // 0..31
  const int a   = j & 7;
  const int sel = j >> 3;
  const int qt  = (sel==0) ? a : (sel==1) ? 15-a : (sel==2) ? 16+a : 31-a;  // balanced map
  const int h   = bh & 15;
  const int b   = bh >> 4;

  const size_t headoff = (size_t)h * 64;
  const size_t bbase   = (size_t)b * 4096;

  // Q fragments, 2 groups of 16 q-rows (B-operand: n=l15=q, k=quad*8+j=d)
  bf16x8 aq[2][2];
  #pragma unroll
  for (int g=0; g<2; g++) {
    int row = qt*128 + w*32 + g*16 + l15;
    const bf16* qp = Q + (bbase + row)*1024 + headoff + quad*8;
    aq[g][0] = *(const bf16x8*)(qp);
    aq[g][1] = *(const bf16x8*)(qp + 32);
  }

  short4v ones_s;
  {
    bf16x4 o1;
    #pragma unroll
    for (int jj=0;jj<4;jj++) o1[jj] = (bf16)1.0f;
    ones_s = __builtin_bit_cast(short4v, o1);
  }

  f32x4 acco[2][4];
  f32x4 accli[2];
  #pragma unroll
  for (int g=0; g<2; g++) {
    accli[g] = (f32x4){0.f,0.f,0.f,0.f};
    #pragma unroll
    for (int i=0;i<4;i++) acco[g][i] = (f32x4){0.f,0.f,0.f,0.f};
  }

  const int kt_row = tid >> 2;
  const int kt_col = (tid & 3) * 16;

  // stage k-tile 0 -> buf 0
  {
    const bf16* kp = Kp + (bbase + kt_row)*1024 + headoff + kt_col;
    bf16x8 k0 = *(const bf16x8*)(kp);
    bf16x8 k1 = *(const bf16x8*)(kp + 8);
    *(bf16x8*)(Ks + kt_row*72 + kt_col)     = k0;
    *(bf16x8*)(Ks + kt_row*72 + kt_col + 8) = k1;
    const bf16* vp = V + (bbase + lane)*1024 + headoff + w*16;
    bf16x8 v0 = *(const bf16x8*)(vp);
    bf16x8 v1 = *(const bf16x8*)(vp + 8);
    #pragma unroll
    for (int jj=0;jj<8;jj++) {
      Vt[(w*16 + jj    )*72 + lane] = v0[jj];
      Vt[(w*16 + 8 + jj)*72 + lane] = v1[jj];
    }
  }
  __syncthreads();

  const int ktmax = 2*qt + 1;
  const int qlo0  = qt*128 + w*32;      // group-0 min q-row of this wave
  const int qhi_w = qlo0 + 31;          // max q-row this wave owns

  for (int kt = 0; kt <= ktmax; ++kt) {
    const int p = kt & 1;
    const bool pre = (kt < ktmax);

    bf16x8 kr0, kr1, vr0, vr1;
    if (pre) {
      const bf16* kp = Kp + (bbase + (size_t)(kt+1)*64 + kt_row)*1024 + headoff + kt_col;
      kr0 = *(const bf16x8*)(kp);
      kr1 = *(const bf16x8*)(kp + 8);
      const bf16* vp = V + (bbase + (size_t)(kt+1)*64 + lane)*1024 + headoff + w*16;
      vr0 = *(const bf16x8*)(vp);
      vr1 = *(const bf16x8*)(vp + 8);
    }

    const int t0 = kt*64;
    if (t0 <= qhi_w) {                  // wave has live q for this k-tile
      const bf16* ksb = Ks + p*4608;
      const bf16* vtb = Vt + p*4608;

      short4v pts[2][4];
      bool alive[2];
      #pragma unroll
      for (int g=0; g<2; g++) {
        const int qlo_g = qlo0 + g*16;
        alive[g] = (t0 <= qlo_g + 15);
        if (alive[g]) {
          f32x4 accs[4];
          #pragma unroll
          for (int i=0;i<4;i++) accs[i] = (f32x4){0.f,0.f,0.f,0.f};
          #pragma unroll
          for (int kk=0;kk<2;kk++) {
            #pragma unroll
            for (int tt=0;tt<4;tt++) {
              bf16x8 ka = *(const bf16x8*)(ksb + (tt*16 + l15)*72 + kk*32 + quad*8);
              accs[tt] = MFMA16(ka, aq[g][kk], accs[tt]);
            }
          }
          const bool needs_mask = (t0 + 63 > qlo_g);
          const int qg = qlo_g + l15;
          #pragma unroll
          for (int tt=0;tt<4;tt++) {
            bf16x4 pb;
            #pragma unroll
            for (int r=0;r<4;r++) {
              float tv = fminf(accs[tt][r] * 0.1803368801f, 60.0f);
              float pf = exp2f(tv);
              if (needs_mask && (t0 + tt*16 + quad*4 + r > qg)) pf = 0.0f;
              pb[r] = (bf16)pf;
            }
            pts[g][tt] = __builtin_bit_cast(short4v, pb);
          }
        }
      }

      // PV with va shared across both groups; li via ones-MFMA
      #pragma unroll
      for (int nt=0;nt<4;nt++) {
        #pragma unroll
        for (int tt=0;tt<4;tt++) {
          bf16x4 va = *(const bf16x4*)(vtb + (nt*16 + l15)*72 + tt*16 + quad*4);
          short4v vas = __builtin_bit_cast(short4v, va);
          acco[0][nt] = MFMAK16(vas, pts[0][tt], acco[0][nt]);
          if (alive[1]) acco[1][nt] = MFMAK16(vas, pts[1][tt], acco[1][nt]);
        }
      }
      #pragma unroll
      for (int tt=0;tt<4;tt++) {
        accli[0] = MFMAK16(ones_s, pts[0][tt], accli[0]);
        if (alive[1]) accli[1] = MFMAK16(ones_s, pts[1][tt], accli[1]);
      }
    }

    if (pre) {
      bf16* ksn = Ks + (p^1)*4608;
      bf16* vtn = Vt + (p^1)*4608;
      *(bf16x8*)(ksn + kt_row*72 + kt_col)     = kr0;
      *(bf16x8*)(ksn + kt_row*72 + kt_col + 8) = kr1;
      #pragma unroll
      for (int jj=0;jj<8;jj++) {
        vtn[(w*16 + jj    )*72 + lane] = vr0[jj];
        vtn[(w*16 + 8 + jj)*72 + lane] = vr1[jj];
      }
      __syncthreads();
    }
  }

  // epilogue: lane holds O^T[d=nt*16+quad*4+r][q=l15] per group
  #pragma unroll
  for (int g=0; g<2; g++) {
    float inv = 1.0f / accli[g][0];
    int qrow = qt*128 + w*32 + g*16 + l15;
    bf16* ob = O + (bbase + qrow)*1024 + headoff;
    #pragma unroll
    for (int nt=0;nt<4;nt++) {
      bf16x4 o;
      #pragma unroll
      for (int r=0;r<4;r++) o[r] = (bf16)(acco[g][nt][r] * inv);
      *(bf16x4*)(ob + nt*16 + quad*4) = o;
    }
  }
}

extern "C" void kernel_launch(void* const* d_in, const int* in_sizes, int n_in,
                              void* d_out, int out_size, void* d_ws, size_t ws_size,
                              hipStream_t stream) {
  const float* x  = (const float*)d_in[0];
  const float* Wq = (const float*)d_in[1];
  const float* bq = (const float*)d_in[2];
  const float* Wk = (const float*)d_in[3];
  const float* bk = (const float*)d_in[4];
  const float* Wv = (const float*)d_in[5];
  const float* bv = (const float*)d_in[6];
  const float* Wo = (const float*)d_in[7];
  const float* bo = (const float*)d_in[8];
  float* out = (float*)d_out;

  // ws (bf16 elems): q 8M | k 8M | v 8M | xb 8M | WtO 1M  (66 MB; r4 proved >=72 MB ok).
  // ao in-place over q (block-exclusive slices). WtQKV (3M el) in d_out scratch
  // (dead before gemm_out writes d_out).
  bf16* ws = (bf16*)d_ws;
  bf16* q  = ws;
  bf16* k  = q + (size_t)8192*1024;
  bf16* v  = k + (size_t)8192*1024;
  bf16* xb = v + (size_t)8192*1024;
  bf16* WtO = xb + (size_t)8192*1024;
  bf16* ao = q;
  bf16* WtQKV = (bf16*)d_out;

  tr_cast4<<<dim3(16,16,4), dim3(64,16), 0, stream>>>(Wq, Wk, Wv, Wo, WtQKV, WtO);
  cast_x<<<4096, 256, 0, stream>>>(x, xb);
  gemm_qkv<<<dim3(24,64), 256, 0, stream>>>(xb, WtQKV, bq, bk, bv, q, k, v, 8192, 1024);
  attn_fwd<<<1024, 256, 0, stream>>>(q, k, v, ao);
  gemm_out<<<dim3(8,64), 256, 0, stream>>>(ao, WtO, bo, out, 8192, 1024, 1024);
}